// Round 8
// baseline (95.514 us; speedup 1.0000x reference)
//
#include <hip/hip_runtime.h>

// Exact (non-approximate) GELU, matching jax.nn.gelu(approximate=False).
__device__ __forceinline__ float gelu_exact(float x) {
    return 0.5f * x * (1.0f + erff(x * 0.7071067811865475f));
}

__device__ __forceinline__ float dot4(float4 a, float4 b) {
    return a.x * b.x + a.y * b.y + a.z * b.z + a.w * b.w;
}

// Full 64-lane wave reduce (sum).
__device__ __forceinline__ float wave_reduce(float acc) {
    #pragma unroll
    for (int off = 32; off >= 1; off >>= 1) acc += __shfl_xor(acc, off);
    return acc;
}

// Whole MLP in ONE workgroup (512 threads = 8 waves); x lives in LDS across
// layers, so no inter-kernel round trips. Each wave owns 32 neurons per
// 256x256 layer: per neuron, lane l holds the float4 W-row chunk at l*4
// (fully coalesced), dot4 against x, 6-stage butterfly reduce. The reduced
// value is lane-selected so lanes 0..31 each end up holding one neuron's
// activation -> a single ds_write_b32 per wave updates xs.
// Weight loads issued in groups of 16 (64 VGPRs in flight) to stay far from
// the spill cliff that killed the round-4/6 prefetch (VGPR cap w/ 1024 thr).
__global__ __launch_bounds__(512, 2) void mlp_kernel(
    const float* __restrict__ W1, const float* __restrict__ b1,
    const float* __restrict__ W2, const float* __restrict__ b2,
    const float* __restrict__ W3, const float* __restrict__ b3,
    const float* __restrict__ W4, const float* __restrict__ b4,
    const float* __restrict__ W5, const float* __restrict__ b5,
    float* __restrict__ wout)
{
    __shared__ __align__(16) float xs[256];
    const int t = threadIdx.x;
    const int w = t >> 6;    // wave 0..7
    const int l = t & 63;    // lane

    // Layer 1: MLP input is [0,0,1,1]; W1 is [256,4] row-major.
    if (t < 256) {
        float4 w1r = *reinterpret_cast<const float4*>(W1 + t * 4);
        xs[t] = gelu_exact(w1r.z + w1r.w + b1[t]);
    }
    __syncthreads();

    const float* Wmats[3] = {W2, W3, W4};
    const float* bvecs[3] = {b2, b3, b4};

    for (int L = 0; L < 3; ++L) {
        // wave w owns neurons j = w*32 .. w*32+31
        const float* Wm = Wmats[L] + (size_t)(w * 32) * 256 + l * 4;
        float4 x4 = *reinterpret_cast<const float4*>(xs + l * 4);
        float myval = 0.f;

        #pragma unroll
        for (int g = 0; g < 2; ++g) {
            float4 wv[16];
            #pragma unroll
            for (int n = 0; n < 16; ++n)
                wv[n] = *reinterpret_cast<const float4*>(Wm + (size_t)(g * 16 + n) * 256);
            #pragma unroll
            for (int n = 0; n < 16; ++n) {
                float r = wave_reduce(dot4(wv[n], x4));
                myval = (l == g * 16 + n) ? r : myval;   // lane (g*16+n) keeps neuron g*16+n
            }
        }

        float bj = bvecs[L][w * 32 + (l & 31)];
        float gv = gelu_exact(myval + bj);               // meaningful for l < 32
        __syncthreads();                                 // all x4 reads done
        if (l < 32) xs[w * 32 + l] = gv;
        __syncthreads();
    }

    // Layer 5: W5 [12,256], no activation. Waves 0..3 handle 3 outputs each.
    if (w < 4) {
        float4 x4 = *reinterpret_cast<const float4*>(xs + l * 4);
        #pragma unroll
        for (int n = 0; n < 3; ++n) {
            const int j = w * 3 + n;
            float4 wv = *reinterpret_cast<const float4*>(W5 + (size_t)j * 256 + l * 4);
            float r = wave_reduce(dot4(wv, x4));
            if (l == 0) wout[j] = r + b5[j];
        }
    }
}

// Kernel B: pred[b,p,d] = sum_c feat[b,c,p] * w[c*3+d].
// feat: [B=4, C=4, HW=65536] fp32, out: [B, HW, 3] fp32.
// Each thread handles 4 consecutive pixels: 4x float4 loads (one per
// channel plane), 48 FMAs, 3x float4 stores (48B contiguous, 16B aligned).
__global__ __launch_bounds__(256) void apply_kernel(
    const float* __restrict__ feat, const float* __restrict__ w12,
    float* __restrict__ out)
{
    const int idx = blockIdx.x * 256 + threadIdx.x;  // 0..65535
    const int b   = idx >> 14;                        // 16384 chunks per batch
    const int pos = (idx & 16383) << 2;               // pixel start (multiple of 4)

    const float* fb = feat + (size_t)b * 4 * 65536 + pos;
    const float4 f0 = *reinterpret_cast<const float4*>(fb);
    const float4 f1 = *reinterpret_cast<const float4*>(fb + 65536);
    const float4 f2 = *reinterpret_cast<const float4*>(fb + 131072);
    const float4 f3 = *reinterpret_cast<const float4*>(fb + 196608);

    float w[12];
    #pragma unroll
    for (int i = 0; i < 12; ++i) w[i] = w12[i];

    float r[12];
    #pragma unroll
    for (int dd = 0; dd < 3; ++dd) {
        r[0 + dd] = f0.x * w[dd] + f1.x * w[3 + dd] + f2.x * w[6 + dd] + f3.x * w[9 + dd];
        r[3 + dd] = f0.y * w[dd] + f1.y * w[3 + dd] + f2.y * w[6 + dd] + f3.y * w[9 + dd];
        r[6 + dd] = f0.z * w[dd] + f1.z * w[3 + dd] + f2.z * w[6 + dd] + f3.z * w[9 + dd];
        r[9 + dd] = f0.w * w[dd] + f1.w * w[3 + dd] + f2.w * w[6 + dd] + f3.w * w[9 + dd];
    }

    float* op = out + (size_t)(b * 65536 + pos) * 3;
    reinterpret_cast<float4*>(op)[0] = make_float4(r[0], r[1], r[2],  r[3]);
    reinterpret_cast<float4*>(op)[1] = make_float4(r[4], r[5], r[6],  r[7]);
    reinterpret_cast<float4*>(op)[2] = make_float4(r[8], r[9], r[10], r[11]);
}

extern "C" void kernel_launch(void* const* d_in, const int* in_sizes, int n_in,
                              void* d_out, int out_size, void* d_ws, size_t ws_size,
                              hipStream_t stream) {
    const float* feat = (const float*)d_in[0];
    const float* W1   = (const float*)d_in[1];
    const float* b1   = (const float*)d_in[2];
    const float* W2   = (const float*)d_in[3];
    const float* b2   = (const float*)d_in[4];
    const float* W3   = (const float*)d_in[5];
    const float* b3   = (const float*)d_in[6];
    const float* W4   = (const float*)d_in[7];
    const float* b4   = (const float*)d_in[8];
    const float* W5   = (const float*)d_in[9];
    const float* b5   = (const float*)d_in[10];

    float* wout = (float*)d_ws;      // 12 floats of scratch
    float* out  = (float*)d_out;     // [4, 65536, 3] fp32

    mlp_kernel <<<1, 512, 0, stream>>>(W1, b1, W2, b2, W3, b3, W4, b4,
                                       W5, b5, wout);
    apply_kernel<<<256, 256, 0, stream>>>(feat, wout, out);
}